// Round 8
// baseline (239.426 us; speedup 1.0000x reference)
//
#include <hip/hip_runtime.h>

// AtomDistances: B=16, A=4096, N=128
//   out[b,a,n] = mask[b,a,n] ? || pos[b,nbr[b,a,n]] - pos[b,a] + co[b,a,n,:] @ cell[b] || : 0
//
// R3: LDS-staged positions  89 -> 70.7 us
// R4/R5: 512 blocks, stage once, 4-slab loop -> <58.6 us (kernel fell out of
//        rocprof top-5; no counters since)
// R6/R7: pipeline / occupancy forcing -> unresolvable (+-1us in totals)
// R8 (DIAGNOSTIC): duplicate the work in-dispatch (grid x2, second half
//     recomputes identical outputs) so the kernel runs ~2x and surfaces in
//     the top-5 WITH counters. Body identical to R7. dur/2 ~= real kernel
//     time. Deliberate one-round total regression to regain observability.

#define A_DIM 4096
#define N_DIM 128
#define B_DIM 16
#define THREADS 1024
#define BLOCKS_PER_BATCH 32                          // 512 logical blocks
#define LOGICAL_BLOCKS (B_DIM * BLOCKS_PER_BATCH)    // 512
#define DUP 2                                        // work duplication factor
#define ATOMS_PER_BLOCK (A_DIM / BLOCKS_PER_BATCH)   // 128
#define SLAB_ATOMS 32                                // 32 atoms * 128 nbr = 4096 = THREADS*4
#define N_SLABS (ATOMS_PER_BLOCK / SLAB_ATOMS)       // 4

typedef int   iv4 __attribute__((ext_vector_type(4)));
typedef float fv4 __attribute__((ext_vector_type(4)));

__global__ __launch_bounds__(THREADS, 8) void atom_distances_kernel(
    const float* __restrict__ positions,     // (B, A, 3)
    const int*   __restrict__ neighbors,     // (B, A, N) int32
    const float* __restrict__ cell,          // (B, 3, 3)
    const float* __restrict__ cell_offsets,  // (B, A, N, 3)
    const int*   __restrict__ mask,          // (B, A, N) int32 (0/1)
    float* __restrict__ out)                 // (B, A, N)
{
    __shared__ fv4 lpos[A_DIM];              // 64 KB — whole batch window

    const int lb     = blockIdx.x % LOGICAL_BLOCKS;      // duplicate halves
    const int b      = lb / BLOCKS_PER_BATCH;            // block-uniform
    const int a_base = (lb % BLOCKS_PER_BATCH) * ATOMS_PER_BLOCK;

    // ---- stage all 4096 batch positions into LDS once (48 KB, L2/L3-hit) ----
    const float* pb = positions + b * (A_DIM * 3);
    for (int j = threadIdx.x; j < A_DIM; j += THREADS) {
        fv4 p = { pb[j * 3 + 0], pb[j * 3 + 1], pb[j * 3 + 2], 0.0f };
        lpos[j] = p;
    }
    __syncthreads();                         // only barrier in the kernel

    const float* cb = cell + b * 9;          // uniform -> sgpr
    const float c00 = cb[0], c01 = cb[1], c02 = cb[2];
    const float c10 = cb[3], c11 = cb[4], c12 = cb[5];
    const float c20 = cb[6], c21 = cb[7], c22 = cb[8];

    const int r = threadIdx.x * 4;           // 0..4095 within a slab

    // ---- rolled streaming loop: minimal live state ----
#pragma unroll 1
    for (int s = 0; s < N_SLABS; ++s) {
        const int a0 = a_base + s * SLAB_ATOMS;
        const int a  = a0 + (r >> 7);                    // r / N_DIM
        const int e  = (b * A_DIM + a0) * N_DIM + r;     // flat element base

        const iv4 nb = __builtin_nontemporal_load((const iv4*)(neighbors + e));
        const iv4 mk = __builtin_nontemporal_load((const iv4*)(mask + e));
        const fv4* co = (const fv4*)(cell_offsets + (size_t)e * 3);
        const fv4 o0 = __builtin_nontemporal_load(co + 0);
        const fv4 o1 = __builtin_nontemporal_load(co + 1);
        const fv4 o2 = __builtin_nontemporal_load(co + 2);

        const fv4 ap = lpos[a];              // LDS broadcast across 32 lanes

        const int jj[4] = { nb.x, nb.y, nb.z, nb.w };
        fv4 pj[4];
#pragma unroll
        for (int k = 0; k < 4; ++k) pj[k] = lpos[jj[k]];   // ds_read_b128 gather

        const int mm[4] = { mk.x, mk.y, mk.z, mk.w };

        float cox[4], coy[4], coz[4];
        cox[0] = o0.x; coy[0] = o0.y; coz[0] = o0.z;
        cox[1] = o0.w; coy[1] = o1.x; coz[1] = o1.y;
        cox[2] = o1.z; coy[2] = o1.w; coz[2] = o2.x;
        cox[3] = o2.y; coy[3] = o2.z; coz[3] = o2.w;

        fv4 res;
#pragma unroll
        for (int k = 0; k < 4; ++k) {
            const float dx = pj[k].x - ap.x + cox[k] * c00 + coy[k] * c10 + coz[k] * c20;
            const float dy = pj[k].y - ap.y + cox[k] * c01 + coy[k] * c11 + coz[k] * c21;
            const float dz = pj[k].z - ap.z + cox[k] * c02 + coy[k] * c12 + coz[k] * c22;
            const float d = __builtin_amdgcn_sqrtf(dx * dx + dy * dy + dz * dz);
            res[k] = mm[k] ? d : 0.0f;
        }

        __builtin_nontemporal_store(res, (fv4*)(out + e));
    }
}

extern "C" void kernel_launch(void* const* d_in, const int* in_sizes, int n_in,
                              void* d_out, int out_size, void* d_ws, size_t ws_size,
                              hipStream_t stream) {
    const float* positions    = (const float*)d_in[0];
    const int*   neighbors    = (const int*)d_in[1];
    const float* cell         = (const float*)d_in[2];
    const float* cell_offsets = (const float*)d_in[3];
    const int*   mask         = (const int*)d_in[4];
    float* out = (float*)d_out;

    const int blocks = LOGICAL_BLOCKS * DUP;   // 1024: halves write identical values
    atom_distances_kernel<<<blocks, THREADS, 0, stream>>>(
        positions, neighbors, cell, cell_offsets, mask, out);
}